// Round 7
// baseline (313.787 us; speedup 1.0000x reference)
//
#include <hip/hip_runtime.h>

#define T_STEPS 512
#define G_CELLS 4096
#define HALF_G  (G_CELLS / 2)
#define L_UHN   15
#define GRP     4
#define RT_T    32                     // outputs per thread in tiled routing
#define PLANE_BYTES ((size_t)T_STEPS * G_CELLS * 4)
#define NZF     1e-5f
#define LOG2E   1.44269504088896340736f
#define LOG2_10 3.32192809488736234787f

// raw gfx950 transcendental units: v_exp_f32 computes 2^x, v_log_f32 computes log2(x)
__device__ __forceinline__ float fexp2(float x) { return __builtin_amdgcn_exp2f(x); }
__device__ __forceinline__ float flog2(float x) { return __builtin_amdgcn_logf(x); }

__device__ __forceinline__ float fpow(float a, float b) {   // a > 0
    return fexp2(b * flog2(a));
}
__device__ __forceinline__ float fexp(float x) {            // e^x
    return fexp2(x * LOG2E);
}
__device__ __forceinline__ float fsigmoid(float v) {
    return 1.0f / (1.0f + fexp(-v));
}
__device__ __forceinline__ float fdescale(float s, float lo, float hi) {
    return lo + s * (hi - lo);
}

// ---- per-cell constants for the scan (no routing params) ----
struct CellC {
    float ddf_min, ddfsum, ddfK, Tbm, Kf, Tbf, SWI, exp_fe, fcsum, fcmin, Ccum;
    float inv_vmax, hbv_beta, vic_beta, hmets_alpha;
    float w1, w2, w3, w4, w5, w6, w8, w9, w7qk, c_b1, c_b2;
    float baseflow_n, quickflow_n, qf_top_coef, mmax, ET_eff, cv2p;
};
struct CellS {
    float sp1, lw1, cm1, sp2, lw2, cm2, sp3, cm3, vad, phr;
};

__device__ __forceinline__ void unpack_consts(const float* __restrict__ pp, CellC& c) {
    float raw[35];
    #pragma unroll
    for (int i = 0; i < 35; ++i) raw[i] = pp[i];

    const float ddf_min     = fdescale(fsigmoid(raw[0]),  0.0f, 20.0f);
    const float ddf_plus    = fdescale(fsigmoid(raw[1]),  0.0f, 20.0f);
    const float Kcum        = fdescale(fsigmoid(raw[2]),  0.01f, 0.2f);
    c.Kf                    = fdescale(fsigmoid(raw[3]),  0.0f, 5.0f);
    c.exp_fe                = fdescale(fsigmoid(raw[4]),  0.0f, 1.0f);
    c.Tbf                   = fdescale(fsigmoid(raw[5]), -5.0f, 2.0f);
    c.Ccum                  = fdescale(fsigmoid(raw[6]),  0.005f, 0.05f);
    c.SWI                   = fdescale(fsigmoid(raw[7]),  0.0f, 0.4f);
    c.Tbm                   = fdescale(fsigmoid(raw[8]), -2.0f, 3.0f);
    c.fcmin                 = fdescale(fsigmoid(raw[9]),  0.0f, 0.1f);
    const float fcmin_plus  = fdescale(fsigmoid(raw[10]), 0.01f, 0.25f);
    const float vmax        = fdescale(fsigmoid(raw[11]), 0.001f, 500.0f);
    c.hmets_alpha           = fdescale(fsigmoid(raw[12]), 0.0f, 1.0f);
    c.vic_beta              = fdescale(fsigmoid(raw[13]), 0.1f, 3.0f);
    c.hbv_beta              = fdescale(fsigmoid(raw[14]), 0.5f, 3.0f);
    const float quickflow_k = fdescale(fsigmoid(raw[15]), -5.0f, -2.0f);
    c.quickflow_n           = fdescale(fsigmoid(raw[16]), 0.5f, 2.0f);
    c.mmax                  = fdescale(fsigmoid(raw[17]), 0.0f, 100.0f);
    const float lamb        = fdescale(fsigmoid(raw[18]), 5.0f, 10.0f);
    const float baseflow_k  = fdescale(fsigmoid(raw[19]), -5.0f, -1.0f);
    c.baseflow_n            = fdescale(fsigmoid(raw[20]), 0.5f, 2.0f);
    c.ET_eff                = fdescale(fsigmoid(raw[21]), 0.0f, 3.0f);
    c.cv2p                  = fdescale(fsigmoid(raw[22]), 1e-5f, 0.02f);

    float w7, w10, w11;
    {
        float m = fmaxf(fmaxf(raw[24], raw[25]), raw[26]);
        float e0 = fexp(raw[24] - m), e1 = fexp(raw[25] - m), e2 = fexp(raw[26] - m);
        float inv = 1.0f / (e0 + e1 + e2);
        c.w1 = e0 * inv; c.w2 = e1 * inv; c.w3 = e2 * inv;
    }
    {
        float m = fmaxf(fmaxf(raw[27], raw[28]), raw[29]);
        float e0 = fexp(raw[27] - m), e1 = fexp(raw[28] - m), e2 = fexp(raw[29] - m);
        float inv = 1.0f / (e0 + e1 + e2);
        c.w4 = e0 * inv; c.w5 = e1 * inv; c.w6 = e2 * inv;
    }
    {
        float m = fmaxf(fmaxf(raw[30], raw[31]), raw[32]);
        float e0 = fexp(raw[30] - m), e1 = fexp(raw[31] - m), e2 = fexp(raw[32] - m);
        float inv = 1.0f / (e0 + e1 + e2);
        w7 = e0 * inv; c.w8 = e1 * inv; c.w9 = e2 * inv;
    }
    {
        float m = fmaxf(raw[33], raw[34]);
        float e0 = fexp(raw[33] - m), e1 = fexp(raw[34] - m);
        float inv = 1.0f / (e0 + e1);
        w10 = e0 * inv; w11 = e1 * inv;
    }

    c.ddf_min     = ddf_min;
    c.ddfsum      = ddf_min + ddf_plus;
    c.ddfK        = ddf_min * Kcum;
    c.inv_vmax    = 1.0f / vmax;
    const float qk10 = fexp2(quickflow_k * LOG2_10);
    const float bk10 = fexp2(baseflow_k * LOG2_10);
    c.qf_top_coef = c.mmax * (vmax / c.quickflow_n) * fexp2(-c.quickflow_n * flog2(lamb));
    c.fcsum       = c.fcmin + fcmin_plus;
    c.c_b1        = w10 * bk10;
    c.c_b2        = w11 * bk10;
    c.w7qk        = w7 * qk10;
}

__device__ __forceinline__ void init_state(CellS& s) {
    s.sp1 = 0.f; s.lw1 = 0.f; s.cm1 = 0.f;
    s.sp2 = 0.f; s.lw2 = 0.f; s.cm2 = 0.f;
    s.sp3 = 0.f; s.cm3 = 0.f; s.vad = 0.f; s.phr = 0.f;
}

__device__ __forceinline__ void step_cell(const CellC& c, CellS& s,
                                          float prcp, float tm, float pet,
                                          float& qt, float& bt) {
    const float rain = (tm > 0.0f) ? prcp : 0.0f;
    const float snow = prcp - rain;
    const float frz_pot = fmaxf(c.Tbf - tm, NZF);

    // --- snobal_hbv ---
    float o1;
    {
        float ddf  = fminf(c.ddfsum, fmaf(c.ddfK, s.cm1, c.ddf_min));
        float pm   = fmaxf(ddf * (tm - c.Tbm), 0.0f);
        float rfz  = fminf(c.Kf * frz_pot, s.lw1);
        s.sp1 = s.sp1 + snow + rfz;
        float melt = fminf(pm, s.sp1 + snow + rfz);   // reference quirk: sp already updated
        s.cm1 = (s.sp1 > NZF) ? (s.cm1 + melt) : 0.0f;
        s.sp1 = fmaxf(s.sp1 - melt, NZF);
        float wret = c.SWI * s.sp1;
        float wtmp = s.lw1 + melt + rain;
        o1 = fmaxf(wtmp - wret, 0.0f);
        s.lw1 = fminf(wtmp, wret);                    // == (ovf>0 ? wret : wtmp)
    }

    // --- snobal_hmets ---
    float o2;
    {
        float ddf  = fminf(c.ddfsum, fmaf(c.ddfK, s.cm2, c.ddf_min));
        float pm   = fmaxf(ddf * (tm - c.Tbm), 0.0f);
        float pfz  = c.Kf * fpow(frz_pot, c.exp_fe);
        float rfz  = fminf(pfz, s.lw2);
        s.lw2 = s.lw2 - rfz;
        s.sp2 = s.sp2 + rfz;
        float melt = fminf(pm, s.sp2 + snow);
        s.sp2 = s.sp2 + snow - melt;
        s.cm2 = (s.sp2 > NZF) ? (s.cm2 + melt) : 0.0f;
        float wrf  = fmaxf(c.fcsum * (1.0f - c.Ccum * s.cm2), c.fcmin);
        float wret = wrf * s.sp2;
        float wtmp = s.lw2 + melt + rain;
        o2 = fmaxf(wtmp - wret, 0.0f);
        s.lw2 = fminf(wtmp, wret);
        s.cm2 = (s.sp2 > NZF) ? (s.cm2 + melt) : 0.0f;  // reference quirk: cm updated twice
    }

    // --- snobal_simple ---
    float o3;
    {
        float ddf  = fminf(c.ddfsum, fmaf(c.ddfK, s.cm3, c.ddf_min));
        float pm   = fmaxf(ddf * (tm - c.Tbm), 0.0f);
        float melt = fminf(pm, s.sp3);
        s.sp3 = s.sp3 + snow - melt;
        o3 = melt + rain;
        s.cm3 = (s.sp3 > NZF) ? (s.cm3 + melt) : 0.0f;
    }

    // --- vadose / phreatic chain ---
    float rr = c.w1 * o1 + c.w2 * o2 + c.w3 * o3;
    float vv = s.vad * c.inv_vmax;
    float sprop = fminf(fmaxf(vv, NZF), 1.0f - NZF);
    float l1 = flog2(1.0f - sprop);
    float phbv = fexp2(c.hbv_beta * l1);
    float pvic = fexp2(c.vic_beta * l1);
    float inf = c.w4 * rr * phbv + c.w5 * rr * (1.0f - c.hmets_alpha * vv) + c.w6 * rr * (1.0f - pvic);
    inf = fminf(fmaxf(inf, 0.0f), rr);
    float surface = rr - inf;
    s.vad += inf;
    vv = s.vad * c.inv_vmax;
    sprop = fminf(fmaxf(vv, NZF), 1.0f - NZF);
    float et = fminf(pet * c.ET_eff * sprop, s.vad);
    s.vad -= et;
    float spq    = fexp2(c.quickflow_n * flog2(sprop));
    float qf_top = fminf(c.qf_top_coef * spq, s.vad);
    float qf_vic = fminf(c.mmax * spq, s.vad);
    float qf = fminf(c.w7qk * s.vad + c.w8 * qf_top + c.w9 * qf_vic, s.vad);
    s.vad -= qf;
    float perc = c.cv2p * s.vad;
    s.vad -= perc;
    s.phr += perc;
    float pb = fexp2(c.baseflow_n * flog2(fmaxf(s.phr, NZF)));
    float bf = fminf(c.c_b1 * s.phr + c.c_b2 * pb, s.phr);
    s.phr -= bf;

    qt = surface + qf;
    bt = bf;
}

__device__ __forceinline__ void make_uh(float a1, float b1, float a2, float b2,
                                        float* uh1, float* uh2) {
    const float LOG2T[L_UHN] = {
        -1.0f, 0.58496250072116f, 1.32192809488736f, 1.80735492205760f,
        2.16992500144231f, 2.45943161863730f, 2.70043971814109f,
        2.90689059560852f, 3.08746284125034f, 3.24792751344359f,
        3.39231742277876f, 3.52356195605701f, 3.64385618977472f,
        3.75488750216347f, 3.85798099512757f };
    float rb1 = LOG2E / b1, rb2 = LOG2E / b2;
    float s1 = 0.0f, s2 = 0.0f;
    #pragma unroll
    for (int k = 0; k < L_UHN; ++k) {
        float tk = (float)k + 0.5f;
        float v1 = fexp2((a1 - 1.0f) * LOG2T[k] - tk * rb1);
        float v2 = fexp2((a2 - 1.0f) * LOG2T[k] - tk * rb2);
        uh1[k] = v1; uh2[k] = v2; s1 += v1; s2 += v2;
    }
    float i1 = 1.0f / s1, i2 = 1.0f / s2;
    #pragma unroll
    for (int k = 0; k < L_UHN; ++k) { uh1[k] *= i1; uh2[k] *= i2; }
}

__device__ __forceinline__ void unpack_route(const float* __restrict__ pp,
                                             float& a1, float& b1, float& a2, float& b2) {
    a1 = fdescale(fsigmoid(pp[35]), 0.3f, 20.0f);
    b1 = fdescale(fsigmoid(pp[36]), 0.01f, 5.0f);
    a2 = fdescale(fsigmoid(pp[37]), 0.5f, 13.0f);
    b2 = fdescale(fsigmoid(pp[38]), 0.15f, 1.5f);
}

// =============== scan kernel: 2 independent cells per thread ===============
__global__ __launch_bounds__(64, 1) void scan2_kernel(
    const float* __restrict__ x,       // (T, G, 3)
    const float* __restrict__ params,  // (T, G, 39)
    float* __restrict__ quick,         // (T, G)
    float* __restrict__ base)          // (T, G)
{
    const int ga = blockIdx.x * 64 + threadIdx.x;   // [0, 2048)
    const int gb = ga + HALF_G;                     // [2048, 4096)

    CellC cca, ccb; CellS sa, sb;
    unpack_consts(params + ((size_t)(T_STEPS - 1) * G_CELLS + (size_t)ga) * 39, cca);
    unpack_consts(params + ((size_t)(T_STEPS - 1) * G_CELLS + (size_t)gb) * 39, ccb);
    init_state(sa); init_state(sb);

    float cxa[GRP][3], nxa[GRP][3], cxb[GRP][3], nxb[GRP][3];
    #pragma unroll
    for (int j = 0; j < GRP; ++j) {
        size_t aa = ((size_t)j * G_CELLS + (size_t)ga) * 3;
        size_t ab = ((size_t)j * G_CELLS + (size_t)gb) * 3;
        cxa[j][0] = x[aa]; cxa[j][1] = x[aa + 1]; cxa[j][2] = x[aa + 2];
        cxb[j][0] = x[ab]; cxb[j][1] = x[ab + 1]; cxb[j][2] = x[ab + 2];
    }

    for (int tb = 0; tb < T_STEPS / GRP; ++tb) {
        const int base_next = (tb + 1) * GRP;
        #pragma unroll
        for (int j = 0; j < GRP; ++j) {
            int tt = base_next + j;
            if (tt >= T_STEPS) tt = T_STEPS - 1;   // harmless clamp for final group
            size_t aa = ((size_t)tt * G_CELLS + (size_t)ga) * 3;
            size_t ab = ((size_t)tt * G_CELLS + (size_t)gb) * 3;
            nxa[j][0] = x[aa]; nxa[j][1] = x[aa + 1]; nxa[j][2] = x[aa + 2];
            nxb[j][0] = x[ab]; nxb[j][1] = x[ab + 1]; nxb[j][2] = x[ab + 2];
        }

        #pragma unroll
        for (int j = 0; j < GRP; ++j) {
            const int t = tb * GRP + j;
            float qa, ba_, qb, bb_;
            step_cell(cca, sa, cxa[j][0], cxa[j][1], cxa[j][2], qa, ba_);
            step_cell(ccb, sb, cxb[j][0], cxb[j][1], cxb[j][2], qb, bb_);
            const size_t row = (size_t)t * G_CELLS;
            quick[row + ga] = qa;  base[row + ga] = ba_;
            quick[row + gb] = qb;  base[row + gb] = bb_;
        }

        #pragma unroll
        for (int j = 0; j < GRP; ++j) {
            cxa[j][0] = nxa[j][0]; cxa[j][1] = nxa[j][1]; cxa[j][2] = nxa[j][2];
            cxb[j][0] = nxb[j][0]; cxb[j][1] = nxb[j][1]; cxb[j][2] = nxb[j][2];
        }
    }
}

// =============== tiled routing: thread computes RT_T outputs for one g ===============
__global__ __launch_bounds__(64, 1) void route_tiled_kernel(
    const float* __restrict__ quick,
    const float* __restrict__ base,
    const float* __restrict__ params,
    float* __restrict__ out)
{
    const int g  = blockIdx.x * 64 + threadIdx.x;
    const int t0 = blockIdx.y * RT_T;

    float a1, b1, a2, b2;
    unpack_route(params + ((size_t)(T_STEPS - 1) * G_CELLS + (size_t)g) * 39, a1, b1, a2, b2);
    float uh1[L_UHN], uh2[L_UHN];
    make_uh(a1, b1, a2, b2, uh1, uh2);

    float qw[RT_T + L_UHN - 1], bw[RT_T + L_UHN - 1];
    #pragma unroll
    for (int i = 0; i < RT_T + L_UHN - 1; ++i) {
        int t = t0 + i - (L_UHN - 1);
        bool ok = (t >= 0);
        size_t a = (size_t)(ok ? t : 0) * G_CELLS + (size_t)g;
        qw[i] = ok ? quick[a] : 0.0f;
        bw[i] = ok ? base[a]  : 0.0f;
    }

    #pragma unroll
    for (int j = 0; j < RT_T; ++j) {
        float acc = 0.0f;
        #pragma unroll
        for (int k = 0; k < L_UHN; ++k)
            acc = fmaf(uh1[k], qw[j + L_UHN - 1 - k], fmaf(uh2[k], bw[j + L_UHN - 1 - k], acc));
        out[(size_t)(t0 + j) * G_CELLS + (size_t)g] = acc;
    }
}

// =============== sequential in-place routing (quick lives in out) ===============
__global__ __launch_bounds__(64, 1) void route_seq_kernel(
    const float* __restrict__ base,
    const float* __restrict__ params,
    float* __restrict__ out)           // also holds quick on entry
{
    const int g = blockIdx.x * 64 + threadIdx.x;

    float a1, b1, a2, b2;
    unpack_route(params + ((size_t)(T_STEPS - 1) * G_CELLS + (size_t)g) * 39, a1, b1, a2, b2);
    float uh1[L_UHN], uh2[L_UHN];
    make_uh(a1, b1, a2, b2, uh1, uh2);

    float fut[L_UHN];
    #pragma unroll
    for (int k = 0; k < L_UHN; ++k) fut[k] = 0.0f;

    for (int t = 0; t < T_STEPS; ++t) {
        const size_t a = (size_t)t * G_CELLS + (size_t)g;
        float qt = out[a];
        float bt = base[a];
        #pragma unroll
        for (int k = 0; k < L_UHN; ++k)
            fut[k] = fmaf(uh1[k], qt, fmaf(uh2[k], bt, fut[k]));
        out[a] = fut[0];
        #pragma unroll
        for (int k = 0; k < L_UHN - 1; ++k) fut[k] = fut[k + 1];
        fut[L_UHN - 1] = 0.0f;
    }
}

// =============== fused fallback (R4 structure) if workspace is too small ===============
__global__ __launch_bounds__(256) void fused_kernel(
    const float* __restrict__ x,
    const float* __restrict__ params,
    float* __restrict__ out)
{
    const int g = blockIdx.x * blockDim.x + threadIdx.x;

    const float* pp = params + ((size_t)(T_STEPS - 1) * G_CELLS + (size_t)g) * 39;
    CellC c; CellS s;
    unpack_consts(pp, c);
    init_state(s);

    float a1, b1, a2, b2;
    unpack_route(pp, a1, b1, a2, b2);
    float uh1[L_UHN], uh2[L_UHN];
    make_uh(a1, b1, a2, b2, uh1, uh2);

    float fut[L_UHN];
    #pragma unroll
    for (int k = 0; k < L_UHN; ++k) fut[k] = 0.0f;

    float cx[8][3], nx[8][3];
    #pragma unroll
    for (int j = 0; j < 8; ++j) {
        size_t a = ((size_t)j * G_CELLS + (size_t)g) * 3;
        cx[j][0] = x[a]; cx[j][1] = x[a + 1]; cx[j][2] = x[a + 2];
    }

    for (int tb = 0; tb < T_STEPS / 8; ++tb) {
        const int base_next = (tb + 1) * 8;
        #pragma unroll
        for (int j = 0; j < 8; ++j) {
            int tt = base_next + j;
            if (tt >= T_STEPS) tt = T_STEPS - 1;
            size_t a = ((size_t)tt * G_CELLS + (size_t)g) * 3;
            nx[j][0] = x[a]; nx[j][1] = x[a + 1]; nx[j][2] = x[a + 2];
        }
        #pragma unroll
        for (int j = 0; j < 8; ++j) {
            const int t = tb * 8 + j;
            float qt, bt;
            step_cell(c, s, cx[j][0], cx[j][1], cx[j][2], qt, bt);
            #pragma unroll
            for (int k = 0; k < L_UHN; ++k)
                fut[k] = fmaf(uh1[k], qt, fmaf(uh2[k], bt, fut[k]));
            out[(size_t)t * G_CELLS + g] = fut[0];
            #pragma unroll
            for (int k = 0; k < L_UHN - 1; ++k) fut[k] = fut[k + 1];
            fut[L_UHN - 1] = 0.0f;
        }
        #pragma unroll
        for (int j = 0; j < 8; ++j) {
            cx[j][0] = nx[j][0]; cx[j][1] = nx[j][1]; cx[j][2] = nx[j][2];
        }
    }
}

extern "C" void kernel_launch(void* const* d_in, const int* in_sizes, int n_in,
                              void* d_out, int out_size, void* d_ws, size_t ws_size,
                              hipStream_t stream) {
    const float* x      = (const float*)d_in[0];
    const float* params = (const float*)d_in[1];
    float* out          = (float*)d_out;

    if (ws_size >= 2 * PLANE_BYTES) {
        float* quick = (float*)d_ws;
        float* base  = (float*)((char*)d_ws + PLANE_BYTES);
        scan2_kernel<<<dim3(HALF_G / 64), dim3(64), 0, stream>>>(x, params, quick, base);
        route_tiled_kernel<<<dim3(G_CELLS / 64, T_STEPS / RT_T), dim3(64), 0, stream>>>(
            quick, base, params, out);
    } else if (ws_size >= PLANE_BYTES) {
        float* base = (float*)d_ws;
        scan2_kernel<<<dim3(HALF_G / 64), dim3(64), 0, stream>>>(x, params, out, base);
        route_seq_kernel<<<dim3(G_CELLS / 64), dim3(64), 0, stream>>>(base, params, out);
    } else {
        fused_kernel<<<dim3(G_CELLS / 256), dim3(256), 0, stream>>>(x, params, out);
    }
}

// Round 8
// 161.870 us; speedup vs baseline: 1.9385x; 1.9385x over previous
//
#include <hip/hip_runtime.h>

#define T_STEPS 512
#define G_CELLS 4096
#define L_UHN   15
#define GRP     4
#define NGRP    (T_STEPS / GRP)
#define RT_T    32                     // outputs per thread in tiled routing
#define PLANE_BYTES ((size_t)T_STEPS * G_CELLS * 4)
#define NZF     1e-5f
#define LOG2E   1.44269504088896340736f
#define LOG2_10 3.32192809488736234787f

// raw gfx950 transcendental units: v_exp_f32 computes 2^x, v_log_f32 computes log2(x)
__device__ __forceinline__ float fexp2(float x) { return __builtin_amdgcn_exp2f(x); }
__device__ __forceinline__ float flog2(float x) { return __builtin_amdgcn_logf(x); }

__device__ __forceinline__ float fpow(float a, float b) {   // a > 0
    return fexp2(b * flog2(a));
}
__device__ __forceinline__ float fexp(float x) {            // e^x
    return fexp2(x * LOG2E);
}
__device__ __forceinline__ float fsigmoid(float v) {
    return 1.0f / (1.0f + fexp(-v));
}
__device__ __forceinline__ float fdescale(float s, float lo, float hi) {
    return lo + s * (hi - lo);
}

// ---- per-cell constants for the scan (no routing params) ----
struct CellC {
    float ddf_min, ddfsum, ddfK, Tbm, Kf, Tbf, SWI, exp_fe, fcsum, fcmin, Ccum;
    float inv_vmax, hbv_beta, vic_beta, hmets_alpha;
    float w1, w2, w3, w4, w5, w6, w8, w9, w7qk, c_b1, c_b2;
    float baseflow_n, quickflow_n, qf_top_coef, mmax, ET_eff, cv2p;
};
struct CellS {
    float sp1, lw1, cm1, sp2, lw2, cm2, sp3, cm3, vad, phr;
};

__device__ __forceinline__ void unpack_consts(const float* __restrict__ pp, CellC& c) {
    float raw[35];
    #pragma unroll
    for (int i = 0; i < 35; ++i) raw[i] = pp[i];

    const float ddf_min     = fdescale(fsigmoid(raw[0]),  0.0f, 20.0f);
    const float ddf_plus    = fdescale(fsigmoid(raw[1]),  0.0f, 20.0f);
    const float Kcum        = fdescale(fsigmoid(raw[2]),  0.01f, 0.2f);
    c.Kf                    = fdescale(fsigmoid(raw[3]),  0.0f, 5.0f);
    c.exp_fe                = fdescale(fsigmoid(raw[4]),  0.0f, 1.0f);
    c.Tbf                   = fdescale(fsigmoid(raw[5]), -5.0f, 2.0f);
    c.Ccum                  = fdescale(fsigmoid(raw[6]),  0.005f, 0.05f);
    c.SWI                   = fdescale(fsigmoid(raw[7]),  0.0f, 0.4f);
    c.Tbm                   = fdescale(fsigmoid(raw[8]), -2.0f, 3.0f);
    c.fcmin                 = fdescale(fsigmoid(raw[9]),  0.0f, 0.1f);
    const float fcmin_plus  = fdescale(fsigmoid(raw[10]), 0.01f, 0.25f);
    const float vmax        = fdescale(fsigmoid(raw[11]), 0.001f, 500.0f);
    c.hmets_alpha           = fdescale(fsigmoid(raw[12]), 0.0f, 1.0f);
    c.vic_beta              = fdescale(fsigmoid(raw[13]), 0.1f, 3.0f);
    c.hbv_beta              = fdescale(fsigmoid(raw[14]), 0.5f, 3.0f);
    const float quickflow_k = fdescale(fsigmoid(raw[15]), -5.0f, -2.0f);
    c.quickflow_n           = fdescale(fsigmoid(raw[16]), 0.5f, 2.0f);
    c.mmax                  = fdescale(fsigmoid(raw[17]), 0.0f, 100.0f);
    const float lamb        = fdescale(fsigmoid(raw[18]), 5.0f, 10.0f);
    const float baseflow_k  = fdescale(fsigmoid(raw[19]), -5.0f, -1.0f);
    c.baseflow_n            = fdescale(fsigmoid(raw[20]), 0.5f, 2.0f);
    c.ET_eff                = fdescale(fsigmoid(raw[21]), 0.0f, 3.0f);
    c.cv2p                  = fdescale(fsigmoid(raw[22]), 1e-5f, 0.02f);

    float w7, w10, w11;
    {
        float m = fmaxf(fmaxf(raw[24], raw[25]), raw[26]);
        float e0 = fexp(raw[24] - m), e1 = fexp(raw[25] - m), e2 = fexp(raw[26] - m);
        float inv = 1.0f / (e0 + e1 + e2);
        c.w1 = e0 * inv; c.w2 = e1 * inv; c.w3 = e2 * inv;
    }
    {
        float m = fmaxf(fmaxf(raw[27], raw[28]), raw[29]);
        float e0 = fexp(raw[27] - m), e1 = fexp(raw[28] - m), e2 = fexp(raw[29] - m);
        float inv = 1.0f / (e0 + e1 + e2);
        c.w4 = e0 * inv; c.w5 = e1 * inv; c.w6 = e2 * inv;
    }
    {
        float m = fmaxf(fmaxf(raw[30], raw[31]), raw[32]);
        float e0 = fexp(raw[30] - m), e1 = fexp(raw[31] - m), e2 = fexp(raw[32] - m);
        float inv = 1.0f / (e0 + e1 + e2);
        w7 = e0 * inv; c.w8 = e1 * inv; c.w9 = e2 * inv;
    }
    {
        float m = fmaxf(raw[33], raw[34]);
        float e0 = fexp(raw[33] - m), e1 = fexp(raw[34] - m);
        float inv = 1.0f / (e0 + e1);
        w10 = e0 * inv; w11 = e1 * inv;
    }

    c.ddf_min     = ddf_min;
    c.ddfsum      = ddf_min + ddf_plus;
    c.ddfK        = ddf_min * Kcum;
    c.inv_vmax    = 1.0f / vmax;
    const float qk10 = fexp2(quickflow_k * LOG2_10);
    const float bk10 = fexp2(baseflow_k * LOG2_10);
    c.qf_top_coef = c.mmax * (vmax / c.quickflow_n) * fexp2(-c.quickflow_n * flog2(lamb));
    c.fcsum       = c.fcmin + fcmin_plus;
    c.c_b1        = w10 * bk10;
    c.c_b2        = w11 * bk10;
    c.w7qk        = w7 * qk10;
}

__device__ __forceinline__ void init_state(CellS& s) {
    s.sp1 = 0.f; s.lw1 = 0.f; s.cm1 = 0.f;
    s.sp2 = 0.f; s.lw2 = 0.f; s.cm2 = 0.f;
    s.sp3 = 0.f; s.cm3 = 0.f; s.vad = 0.f; s.phr = 0.f;
}

__device__ __forceinline__ void step_cell(const CellC& c, CellS& s,
                                          float prcp, float tm, float pet,
                                          float& qt, float& bt) {
    const float rain = (tm > 0.0f) ? prcp : 0.0f;
    const float snow = prcp - rain;
    const float frz_pot = fmaxf(c.Tbf - tm, NZF);

    // --- snobal_hbv ---
    float o1;
    {
        float ddf  = fminf(c.ddfsum, fmaf(c.ddfK, s.cm1, c.ddf_min));
        float pm   = fmaxf(ddf * (tm - c.Tbm), 0.0f);
        float rfz  = fminf(c.Kf * frz_pot, s.lw1);
        s.sp1 = s.sp1 + snow + rfz;
        float melt = fminf(pm, s.sp1 + snow + rfz);   // reference quirk: sp already updated
        s.cm1 = (s.sp1 > NZF) ? (s.cm1 + melt) : 0.0f;
        s.sp1 = fmaxf(s.sp1 - melt, NZF);
        float wret = c.SWI * s.sp1;
        float wtmp = s.lw1 + melt + rain;
        o1 = fmaxf(wtmp - wret, 0.0f);
        s.lw1 = fminf(wtmp, wret);                    // == (ovf>0 ? wret : wtmp)
    }

    // --- snobal_hmets ---
    float o2;
    {
        float ddf  = fminf(c.ddfsum, fmaf(c.ddfK, s.cm2, c.ddf_min));
        float pm   = fmaxf(ddf * (tm - c.Tbm), 0.0f);
        float pfz  = c.Kf * fpow(frz_pot, c.exp_fe);
        float rfz  = fminf(pfz, s.lw2);
        s.lw2 = s.lw2 - rfz;
        s.sp2 = s.sp2 + rfz;
        float melt = fminf(pm, s.sp2 + snow);
        s.sp2 = s.sp2 + snow - melt;
        s.cm2 = (s.sp2 > NZF) ? (s.cm2 + melt) : 0.0f;
        float wrf  = fmaxf(c.fcsum * (1.0f - c.Ccum * s.cm2), c.fcmin);
        float wret = wrf * s.sp2;
        float wtmp = s.lw2 + melt + rain;
        o2 = fmaxf(wtmp - wret, 0.0f);
        s.lw2 = fminf(wtmp, wret);
        s.cm2 = (s.sp2 > NZF) ? (s.cm2 + melt) : 0.0f;  // reference quirk: cm updated twice
    }

    // --- snobal_simple ---
    float o3;
    {
        float ddf  = fminf(c.ddfsum, fmaf(c.ddfK, s.cm3, c.ddf_min));
        float pm   = fmaxf(ddf * (tm - c.Tbm), 0.0f);
        float melt = fminf(pm, s.sp3);
        s.sp3 = s.sp3 + snow - melt;
        o3 = melt + rain;
        s.cm3 = (s.sp3 > NZF) ? (s.cm3 + melt) : 0.0f;
    }

    // --- vadose / phreatic chain ---
    float rr = c.w1 * o1 + c.w2 * o2 + c.w3 * o3;
    float vv = s.vad * c.inv_vmax;
    float sprop = fminf(fmaxf(vv, NZF), 1.0f - NZF);
    float l1 = flog2(1.0f - sprop);
    float phbv = fexp2(c.hbv_beta * l1);
    float pvic = fexp2(c.vic_beta * l1);
    float inf = c.w4 * rr * phbv + c.w5 * rr * (1.0f - c.hmets_alpha * vv) + c.w6 * rr * (1.0f - pvic);
    inf = fminf(fmaxf(inf, 0.0f), rr);
    float surface = rr - inf;
    s.vad += inf;
    vv = s.vad * c.inv_vmax;
    sprop = fminf(fmaxf(vv, NZF), 1.0f - NZF);
    float et = fminf(pet * c.ET_eff * sprop, s.vad);
    s.vad -= et;
    float spq    = fexp2(c.quickflow_n * flog2(sprop));
    float qf_top = fminf(c.qf_top_coef * spq, s.vad);
    float qf_vic = fminf(c.mmax * spq, s.vad);
    float qf = fminf(c.w7qk * s.vad + c.w8 * qf_top + c.w9 * qf_vic, s.vad);
    s.vad -= qf;
    float perc = c.cv2p * s.vad;
    s.vad -= perc;
    s.phr += perc;
    float pb = fexp2(c.baseflow_n * flog2(fmaxf(s.phr, NZF)));
    float bf = fminf(c.c_b1 * s.phr + c.c_b2 * pb, s.phr);
    s.phr -= bf;

    qt = surface + qf;
    bt = bf;
}

__device__ __forceinline__ void make_uh(float a1, float b1, float a2, float b2,
                                        float* uh1, float* uh2) {
    const float LOG2T[L_UHN] = {
        -1.0f, 0.58496250072116f, 1.32192809488736f, 1.80735492205760f,
        2.16992500144231f, 2.45943161863730f, 2.70043971814109f,
        2.90689059560852f, 3.08746284125034f, 3.24792751344359f,
        3.39231742277876f, 3.52356195605701f, 3.64385618977472f,
        3.75488750216347f, 3.85798099512757f };
    float rb1 = LOG2E / b1, rb2 = LOG2E / b2;
    float s1 = 0.0f, s2 = 0.0f;
    #pragma unroll
    for (int k = 0; k < L_UHN; ++k) {
        float tk = (float)k + 0.5f;
        float v1 = fexp2((a1 - 1.0f) * LOG2T[k] - tk * rb1);
        float v2 = fexp2((a2 - 1.0f) * LOG2T[k] - tk * rb2);
        uh1[k] = v1; uh2[k] = v2; s1 += v1; s2 += v2;
    }
    float i1 = 1.0f / s1, i2 = 1.0f / s2;
    #pragma unroll
    for (int k = 0; k < L_UHN; ++k) { uh1[k] *= i1; uh2[k] *= i2; }
}

__device__ __forceinline__ void unpack_route(const float* __restrict__ pp,
                                             float& a1, float& b1, float& a2, float& b2) {
    a1 = fdescale(fsigmoid(pp[35]), 0.3f, 20.0f);
    b1 = fdescale(fsigmoid(pp[36]), 0.01f, 5.0f);
    a2 = fdescale(fsigmoid(pp[37]), 0.5f, 13.0f);
    b2 = fdescale(fsigmoid(pp[38]), 0.15f, 1.5f);
}

// =============== scan kernel: 1 cell/thread, distance-2 prefetch ===============
__global__ __launch_bounds__(256, 1) void scan1_kernel(
    const float* __restrict__ x,       // (T, G, 3)
    const float* __restrict__ params,  // (T, G, 39)
    float* __restrict__ quick,         // (T, G)
    float* __restrict__ base)          // (T, G)
{
    const int g = blockIdx.x * 256 + threadIdx.x;

    CellC c; CellS s;
    unpack_consts(params + ((size_t)(T_STEPS - 1) * G_CELLS + (size_t)g) * 39, c);
    init_state(s);

    // triple-buffered forcing: compute on A, B is in regs, C being loaded (2 groups ahead)
    float bufA[GRP][3], bufB[GRP][3], bufC[GRP][3];
    #pragma unroll
    for (int j = 0; j < GRP; ++j) {
        size_t a = ((size_t)j * G_CELLS + (size_t)g) * 3;
        bufA[j][0] = x[a]; bufA[j][1] = x[a + 1]; bufA[j][2] = x[a + 2];
    }
    #pragma unroll
    for (int j = 0; j < GRP; ++j) {
        size_t a = ((size_t)(GRP + j) * G_CELLS + (size_t)g) * 3;
        bufB[j][0] = x[a]; bufB[j][1] = x[a + 1]; bufB[j][2] = x[a + 2];
    }

    for (int tb = 0; tb < NGRP; ++tb) {
        // issue loads for group tb+2 (clamped on tail; redundant loads harmless)
        int tn = tb + 2;
        if (tn >= NGRP) tn = NGRP - 1;
        #pragma unroll
        for (int j = 0; j < GRP; ++j) {
            size_t a = ((size_t)(tn * GRP + j) * G_CELLS + (size_t)g) * 3;
            bufC[j][0] = x[a]; bufC[j][1] = x[a + 1]; bufC[j][2] = x[a + 2];
        }

        #pragma unroll
        for (int j = 0; j < GRP; ++j) {
            const int t = tb * GRP + j;
            float qt, bt;
            step_cell(c, s, bufA[j][0], bufA[j][1], bufA[j][2], qt, bt);
            const size_t row = (size_t)t * G_CELLS + (size_t)g;
            quick[row] = qt;
            base[row]  = bt;
        }

        // rotate A <- B <- C (register moves, largely renamed away)
        #pragma unroll
        for (int j = 0; j < GRP; ++j) {
            bufA[j][0] = bufB[j][0]; bufA[j][1] = bufB[j][1]; bufA[j][2] = bufB[j][2];
            bufB[j][0] = bufC[j][0]; bufB[j][1] = bufC[j][1]; bufB[j][2] = bufC[j][2];
        }
    }
}

// =============== tiled routing: thread computes RT_T outputs for one g ===============
__global__ __launch_bounds__(64, 1) void route_tiled_kernel(
    const float* __restrict__ quick,
    const float* __restrict__ base,
    const float* __restrict__ params,
    float* __restrict__ out)
{
    const int g  = blockIdx.x * 64 + threadIdx.x;
    const int t0 = blockIdx.y * RT_T;

    float a1, b1, a2, b2;
    unpack_route(params + ((size_t)(T_STEPS - 1) * G_CELLS + (size_t)g) * 39, a1, b1, a2, b2);
    float uh1[L_UHN], uh2[L_UHN];
    make_uh(a1, b1, a2, b2, uh1, uh2);

    float qw[RT_T + L_UHN - 1], bw[RT_T + L_UHN - 1];
    #pragma unroll
    for (int i = 0; i < RT_T + L_UHN - 1; ++i) {
        int t = t0 + i - (L_UHN - 1);
        bool ok = (t >= 0);
        size_t a = (size_t)(ok ? t : 0) * G_CELLS + (size_t)g;
        qw[i] = ok ? quick[a] : 0.0f;
        bw[i] = ok ? base[a]  : 0.0f;
    }

    #pragma unroll
    for (int j = 0; j < RT_T; ++j) {
        float acc = 0.0f;
        #pragma unroll
        for (int k = 0; k < L_UHN; ++k)
            acc = fmaf(uh1[k], qw[j + L_UHN - 1 - k], fmaf(uh2[k], bw[j + L_UHN - 1 - k], acc));
        out[(size_t)(t0 + j) * G_CELLS + (size_t)g] = acc;
    }
}

// =============== sequential in-place routing (quick lives in out) ===============
__global__ __launch_bounds__(64, 1) void route_seq_kernel(
    const float* __restrict__ base,
    const float* __restrict__ params,
    float* __restrict__ out)           // also holds quick on entry
{
    const int g = blockIdx.x * 64 + threadIdx.x;

    float a1, b1, a2, b2;
    unpack_route(params + ((size_t)(T_STEPS - 1) * G_CELLS + (size_t)g) * 39, a1, b1, a2, b2);
    float uh1[L_UHN], uh2[L_UHN];
    make_uh(a1, b1, a2, b2, uh1, uh2);

    float fut[L_UHN];
    #pragma unroll
    for (int k = 0; k < L_UHN; ++k) fut[k] = 0.0f;

    for (int t = 0; t < T_STEPS; ++t) {
        const size_t a = (size_t)t * G_CELLS + (size_t)g;
        float qt = out[a];
        float bt = base[a];
        #pragma unroll
        for (int k = 0; k < L_UHN; ++k)
            fut[k] = fmaf(uh1[k], qt, fmaf(uh2[k], bt, fut[k]));
        out[a] = fut[0];
        #pragma unroll
        for (int k = 0; k < L_UHN - 1; ++k) fut[k] = fut[k + 1];
        fut[L_UHN - 1] = 0.0f;
    }
}

// =============== fused fallback (R4 structure) if workspace is too small ===============
__global__ __launch_bounds__(256) void fused_kernel(
    const float* __restrict__ x,
    const float* __restrict__ params,
    float* __restrict__ out)
{
    const int g = blockIdx.x * blockDim.x + threadIdx.x;

    const float* pp = params + ((size_t)(T_STEPS - 1) * G_CELLS + (size_t)g) * 39;
    CellC c; CellS s;
    unpack_consts(pp, c);
    init_state(s);

    float a1, b1, a2, b2;
    unpack_route(pp, a1, b1, a2, b2);
    float uh1[L_UHN], uh2[L_UHN];
    make_uh(a1, b1, a2, b2, uh1, uh2);

    float fut[L_UHN];
    #pragma unroll
    for (int k = 0; k < L_UHN; ++k) fut[k] = 0.0f;

    float cx[8][3], nx[8][3];
    #pragma unroll
    for (int j = 0; j < 8; ++j) {
        size_t a = ((size_t)j * G_CELLS + (size_t)g) * 3;
        cx[j][0] = x[a]; cx[j][1] = x[a + 1]; cx[j][2] = x[a + 2];
    }

    for (int tb = 0; tb < T_STEPS / 8; ++tb) {
        const int base_next = (tb + 1) * 8;
        #pragma unroll
        for (int j = 0; j < 8; ++j) {
            int tt = base_next + j;
            if (tt >= T_STEPS) tt = T_STEPS - 1;
            size_t a = ((size_t)tt * G_CELLS + (size_t)g) * 3;
            nx[j][0] = x[a]; nx[j][1] = x[a + 1]; nx[j][2] = x[a + 2];
        }
        #pragma unroll
        for (int j = 0; j < 8; ++j) {
            const int t = tb * 8 + j;
            float qt, bt;
            step_cell(c, s, cx[j][0], cx[j][1], cx[j][2], qt, bt);
            #pragma unroll
            for (int k = 0; k < L_UHN; ++k)
                fut[k] = fmaf(uh1[k], qt, fmaf(uh2[k], bt, fut[k]));
            out[(size_t)t * G_CELLS + g] = fut[0];
            #pragma unroll
            for (int k = 0; k < L_UHN - 1; ++k) fut[k] = fut[k + 1];
            fut[L_UHN - 1] = 0.0f;
        }
        #pragma unroll
        for (int j = 0; j < 8; ++j) {
            cx[j][0] = nx[j][0]; cx[j][1] = nx[j][1]; cx[j][2] = nx[j][2];
        }
    }
}

extern "C" void kernel_launch(void* const* d_in, const int* in_sizes, int n_in,
                              void* d_out, int out_size, void* d_ws, size_t ws_size,
                              hipStream_t stream) {
    const float* x      = (const float*)d_in[0];
    const float* params = (const float*)d_in[1];
    float* out          = (float*)d_out;

    if (ws_size >= 2 * PLANE_BYTES) {
        float* quick = (float*)d_ws;
        float* base  = (float*)((char*)d_ws + PLANE_BYTES);
        scan1_kernel<<<dim3(G_CELLS / 256), dim3(256), 0, stream>>>(x, params, quick, base);
        route_tiled_kernel<<<dim3(G_CELLS / 64, T_STEPS / RT_T), dim3(64), 0, stream>>>(
            quick, base, params, out);
    } else if (ws_size >= PLANE_BYTES) {
        float* base = (float*)d_ws;
        scan1_kernel<<<dim3(G_CELLS / 256), dim3(256), 0, stream>>>(x, params, out, base);
        route_seq_kernel<<<dim3(G_CELLS / 64), dim3(64), 0, stream>>>(base, params, out);
    } else {
        fused_kernel<<<dim3(G_CELLS / 256), dim3(256), 0, stream>>>(x, params, out);
    }
}